// Round 2
// baseline (577.419 us; speedup 1.0000x reference)
//
#include <hip/hip_runtime.h>
#include <stdint.h>

#define BN 4
#define SN 4096
#define EN 256
#define PN 32
#define FN 1024
#define BS (BN*SN)   // 16384

typedef uint16_t bf16_t;
typedef short v4s  __attribute__((ext_vector_type(4)));
typedef short v8s  __attribute__((ext_vector_type(8)));
typedef __bf16 bf16x8 __attribute__((ext_vector_type(8)));
typedef float v4f  __attribute__((ext_vector_type(4)));

__device__ __forceinline__ float b2f(bf16_t x){
    uint32_t u = ((uint32_t)x) << 16; float f; __builtin_memcpy(&f, &u, 4); return f;
}
__device__ __forceinline__ bf16_t f2b(float f){
    uint32_t u; __builtin_memcpy(&u, &f, 4);
    u += 0x7FFFu + ((u >> 16) & 1u);           // RNE
    return (bf16_t)(u >> 16);
}
__device__ __forceinline__ bf16x8 ldb8(const bf16_t* p){
    v8s r = *(const v8s*)p; return __builtin_bit_cast(bf16x8, r);
}
// residual loads / output stores in either precision
__device__ __forceinline__ float ldsc(const float* p){ return *p; }
__device__ __forceinline__ float ldsc(const bf16_t* p){ return b2f(*p); }
__device__ __forceinline__ void stsc(float* p, float v){ *p = v; }
__device__ __forceinline__ void stsc(bf16_t* p, float v){ *p = f2b(v); }

// ---------------------------------------------------------------------------
// Kernel 0: fp32 -> bf16 conversion (n divisible by 1024; 4 elems/thread)
// ---------------------------------------------------------------------------
__global__ __launch_bounds__(256) void cvt_kernel(
    const float* __restrict__ in, bf16_t* __restrict__ out)
{
    int i = (blockIdx.x * 256 + threadIdx.x) * 4;
    float4 f = *(const float4*)(in + i);
    v4s o;
    o.x = (short)f2b(f.x); o.y = (short)f2b(f.y);
    o.z = (short)f2b(f.z); o.w = (short)f2b(f.w);
    *(v4s*)(out + i) = o;
}

// ---------------------------------------------------------------------------
// Kernel 1: pe = Wpos @ pos_embed + bpos  ->  xs = pe^T / ls (bf16), sq = |xs|^2
// ---------------------------------------------------------------------------
__global__ __launch_bounds__(256) void posxs_kernel(
    const float* __restrict__ pos, const float* __restrict__ Wp,
    const float* __restrict__ bp,  const float* __restrict__ lsp,
    bf16_t* __restrict__ xs, float* __restrict__ sq)
{
    __shared__ float Wsh[PN*PN];
    __shared__ float bsh[PN];
    int tid = threadIdx.x;
    for (int i = tid; i < PN*PN; i += 256) Wsh[i] = Wp[i];
    if (tid < PN) bsh[tid] = bp[tid];
    __syncthreads();

    int s = blockIdx.x * 256 + tid;
    int b = blockIdx.y;
    float inv_ls = 1.0f / lsp[0];

    float col[PN];
    #pragma unroll
    for (int p = 0; p < PN; p++) col[p] = pos[((size_t)b*PN + p)*SN + s];

    size_t xbase = ((size_t)b*SN + s) * PN;
    float sqv = 0.f;
    #pragma unroll 4
    for (int o = 0; o < PN; o++){
        float pe = bsh[o];
        #pragma unroll
        for (int p = 0; p < PN; p++) pe += col[p] * Wsh[o*PN + p];
        bf16_t xb = f2b(pe * inv_ls);
        xs[xbase + o] = xb;
        float xr = b2f(xb);
        sqv += xr * xr;       // consistent with the bf16 values the MFMAs will see
    }
    sq[(size_t)b*SN + s] = sqv;
}

// ---------------------------------------------------------------------------
// Generic NT GEMM: out[m][n] = sum_k A[m][k] * W[n][k]  (+ epilogues)
// A, W are bf16; bias/gamma/beta fp32; res/out either precision.
// EPI 0: +bias ; EPI 1: relu(+bias) ; EPI 2: +bias+res -> LayerNorm(N=256)
// block = 256 thr (4 waves); block tile 64 rows x 256 cols; wave = 16 rows.
// ---------------------------------------------------------------------------
template<int EPI, typename OutT, typename ResT>
__global__ __launch_bounds__(256) void gemm_nt(
    const bf16_t* __restrict__ A, const bf16_t* __restrict__ W,
    const float* __restrict__ bias, const ResT* __restrict__ res,
    const float* __restrict__ gamma, const float* __restrict__ beta,
    OutT* __restrict__ out, int M, int N, int K)
{
    int lane = threadIdx.x & 63;
    int wv   = threadIdx.x >> 6;
    int col  = lane & 15;
    int quad = lane >> 4;
    int row0 = blockIdx.x * 64 + wv * 16;
    int n0   = blockIdx.y * 256;

    const bf16_t* Arow  = A + (size_t)(row0 + col) * K + quad * 8;
    const bf16_t* Wbase = W + (size_t)(n0 + col) * K + quad * 8;

    v4f acc[16];
    #pragma unroll
    for (int t = 0; t < 16; t++) acc[t] = (v4f){0.f,0.f,0.f,0.f};

    for (int ks = 0; ks < K; ks += 32){
        bf16x8 a = ldb8(Arow + ks);
        #pragma unroll
        for (int t = 0; t < 16; t++){
            bf16x8 bfr = ldb8(Wbase + (size_t)t * 16 * K + ks);
            acc[t] = __builtin_amdgcn_mfma_f32_16x16x32_bf16(a, bfr, acc[t], 0, 0, 0);
        }
    }

    float bfv[16];
    #pragma unroll
    for (int t = 0; t < 16; t++) bfv[t] = bias[n0 + t*16 + col];

    if constexpr (EPI == 2){
        float gf[16], btf[16];
        #pragma unroll
        for (int t = 0; t < 16; t++){
            gf[t]  = gamma[t*16 + col];
            btf[t] = beta [t*16 + col];
        }
        #pragma unroll
        for (int r = 0; r < 4; r++){
            int row = row0 + quad*4 + r;
            float s1 = 0.f, s2 = 0.f;
            #pragma unroll
            for (int t = 0; t < 16; t++){
                float y = acc[t][r] + bfv[t] + ldsc(res + (size_t)row*N + n0 + t*16 + col);
                acc[t][r] = y;
                s1 += y; s2 += y*y;
            }
            #pragma unroll
            for (int m = 1; m <= 8; m <<= 1){
                s1 += __shfl_xor(s1, m);
                s2 += __shfl_xor(s2, m);
            }
            float mu  = s1 * (1.f/256.f);
            float var = s2 * (1.f/256.f) - mu*mu;
            float rs  = rsqrtf(var + 1e-5f);
            #pragma unroll
            for (int t = 0; t < 16; t++)
                stsc(out + (size_t)row*N + n0 + t*16 + col, (acc[t][r]-mu)*rs*gf[t] + btf[t]);
        }
    } else {
        #pragma unroll
        for (int r = 0; r < 4; r++){
            int row = row0 + quad*4 + r;
            #pragma unroll
            for (int t = 0; t < 16; t++){
                float y = acc[t][r] + bfv[t];
                if constexpr (EPI == 1) y = fmaxf(y, 0.f);
                stsc(out + (size_t)row*N + n0 + t*16 + col, y);
            }
        }
    }
}

// ---------------------------------------------------------------------------
// Kernel 3: flash-style RBF-kernel attention.
//   sc = os*exp(-0.5*d2) in (0, os] -> softmax max is the constant os (exact).
//   w(q,k) = exp(sc - os); ctx[q,:] = sum_k w*v[k,:] / sum_k w.  No S x S matrix.
// block = 256 thr (4 waves), 64 queries/block (16/wave), K-loop chunk 32.
// ---------------------------------------------------------------------------
#define VSTR 40   // LDS row stride: word-stride 20 -> conflict-free b128
__global__ __launch_bounds__(256) void attn_kernel(
    const bf16_t* __restrict__ xs, const float* __restrict__ sq,
    const bf16_t* __restrict__ v,  const float* __restrict__ osp,
    bf16_t* __restrict__ ctx)
{
    __shared__ __align__(16) bf16_t Vt[EN * VSTR];      // [e][k] transposed, 20 KB
    __shared__ __align__(16) bf16_t Wt[4][16 * VSTR];   // per-wave w tiles [q][k]

    int tid  = threadIdx.x;
    int lane = tid & 63;
    int wv   = tid >> 6;
    int col  = lane & 15;
    int quad = lane >> 4;

    // XCD-aware swizzle: each XCD sees exactly one batch b -> V/xs stay L2-resident
    int bid = blockIdx.x;
    int xcd = bid & 7;
    int b   = xcd & 3;
    int qb  = (bid >> 3) + ((xcd >> 2) << 5);
    int q0  = qb * 64;

    float os = osp[0];
    const bf16_t* xsb = xs + (size_t)b * SN * PN;
    const float*  sqb = sq + (size_t)b * SN;
    const bf16_t* vb  = v  + (size_t)b * SN * EN;

    bf16x8 aq = ldb8(xsb + (size_t)(q0 + wv*16 + col) * PN + quad * 8);
    float sqq[4];
    #pragma unroll
    for (int r = 0; r < 4; r++) sqq[r] = sqb[q0 + wv*16 + quad*4 + r];

    v4f acc[16];
    #pragma unroll
    for (int t = 0; t < 16; t++) acc[t] = (v4f){0.f,0.f,0.f,0.f};
    float denp[4] = {0.f, 0.f, 0.f, 0.f};
    const v4f zero = (v4f){0.f,0.f,0.f,0.f};

    for (int k0 = 0; k0 < SN; k0 += 32){
        __syncthreads();   // previous iteration's Vt reads done
        {   // stage V transposed: thread tid owns column e = tid
            const bf16_t* vp = vb + (size_t)k0 * EN + tid;
            v8s pack[4];
            #pragma unroll
            for (int c = 0; c < 4; c++){
                #pragma unroll
                for (int j = 0; j < 8; j++)
                    ((short*)&pack[c])[j] = (short)vp[(size_t)(c*8 + j) * EN];
            }
            #pragma unroll
            for (int c = 0; c < 4; c++)
                *(v8s*)&Vt[(size_t)tid * VSTR + c*8] = pack[c];
        }
        __syncthreads();   // Vt ready

        // scores for this wave's 16 q x 32 k
        #pragma unroll
        for (int h = 0; h < 2; h++){
            bf16x8 bk = ldb8(xsb + (size_t)(k0 + h*16 + col) * PN + quad * 8);
            v4f dot = __builtin_amdgcn_mfma_f32_16x16x32_bf16(aq, bk, zero, 0, 0, 0);
            float sqk = sqb[k0 + h*16 + col];
            #pragma unroll
            for (int r = 0; r < 4; r++){
                float d2 = fmaxf(sqq[r] + sqk - 2.f * dot[r], 0.f);
                float sc = os * exp2f(-0.7213475204444817f * d2);   // exp(-0.5*d2)
                float w  = exp2f(1.4426950408889634f * (sc - os));  // exp(sc-os) <= 1
                bf16_t wb = f2b(w);
                denp[r] += b2f(wb);   // consistent with bf16 weights fed to MFMA
                Wt[wv][(quad*4 + r) * VSTR + h*16 + col] = wb;
            }
        }
        __syncthreads();   // Wt visible

        bf16x8 wa = ldb8(&Wt[wv][col * VSTR + quad * 8]);
        #pragma unroll
        for (int t = 0; t < 16; t++){
            bf16x8 vfr = ldb8(&Vt[(size_t)(t*16 + col) * VSTR + quad * 8]);
            acc[t] = __builtin_amdgcn_mfma_f32_16x16x32_bf16(wa, vfr, acc[t], 0, 0, 0);
        }
    }

    float inv[4];
    #pragma unroll
    for (int r = 0; r < 4; r++){
        float d = denp[r];
        #pragma unroll
        for (int m = 1; m <= 8; m <<= 1) d += __shfl_xor(d, m);
        inv[r] = 1.f / d;
    }
    #pragma unroll
    for (int t = 0; t < 16; t++)
        #pragma unroll
        for (int r = 0; r < 4; r++)
            ctx[((size_t)b*SN + q0 + wv*16 + quad*4 + r) * EN + t*16 + col] = f2b(acc[t][r] * inv[r]);
}

// ---------------------------------------------------------------------------
extern "C" void kernel_launch(void* const* d_in, const int* in_sizes, int n_in,
                              void* d_out, int out_size, void* d_ws, size_t ws_size,
                              hipStream_t stream)
{
    (void)in_sizes; (void)n_in; (void)out_size; (void)ws_size;
    const float* src  = (const float*)d_in[0];
    const float* pos  = (const float*)d_in[1];
    const float* Wpos = (const float*)d_in[2];
    const float* bpos = (const float*)d_in[3];
    const float* ls   = (const float*)d_in[4];
    const float* os   = (const float*)d_in[5];
    const float* Wv   = (const float*)d_in[6];
    const float* bv   = (const float*)d_in[7];
    const float* Wo   = (const float*)d_in[8];
    const float* bo   = (const float*)d_in[9];
    const float* W1   = (const float*)d_in[10];
    const float* b1   = (const float*)d_in[11];
    const float* W2   = (const float*)d_in[12];
    const float* b2   = (const float*)d_in[13];
    const float* g1   = (const float*)d_in[14];
    const float* be1  = (const float*)d_in[15];
    const float* g2   = (const float*)d_in[16];
    const float* be2  = (const float*)d_in[17];

    // workspace layout (bytes)
    char* w = (char*)d_ws;
    bf16_t* xs   = (bf16_t*)(w);                          //  1 MB   [B,S,P]
    float*  sqv  = (float* )(w + (1u<<20));               // 64 KB   [B,S]
    bf16_t* Wvb  = (bf16_t*)(w + (1u<<20) + (1u<<17));    // 128 KB
    bf16_t* Wob  = (bf16_t*)(w + (1u<<20) + (2u<<17));    // 128 KB
    bf16_t* W1b  = (bf16_t*)(w + (1u<<20) + (3u<<17));    // 512 KB
    bf16_t* W2b  = (bf16_t*)(w + (1u<<20) + (7u<<17));    // 512 KB
    bf16_t* vws  = (bf16_t*)(w + ( 3u<<20));              //  8 MB   [B,S,E]
    bf16_t* ctx  = (bf16_t*)(w + (11u<<20));              //  8 MB
    bf16_t* xws  = (bf16_t*)(w + (19u<<20));              //  8 MB
    bf16_t* hws  = (bf16_t*)(w + (27u<<20));              // 32 MB   [B,S,F]
    bf16_t* srcb = (bf16_t*)(w + (27u<<20));              // aliases hws: src_bf16
                                                          // dead before hws written

    // fp32 -> bf16 conversions (n/1024 blocks each; all sizes divisible by 1024)
    cvt_kernel<<<dim3((BS*EN)>>10), 256, 0, stream>>>(src, srcb);
    cvt_kernel<<<dim3((EN*EN)>>10), 256, 0, stream>>>(Wv, Wvb);
    cvt_kernel<<<dim3((EN*EN)>>10), 256, 0, stream>>>(Wo, Wob);
    cvt_kernel<<<dim3((FN*EN)>>10), 256, 0, stream>>>(W1, W1b);
    cvt_kernel<<<dim3((EN*FN)>>10), 256, 0, stream>>>(W2, W2b);

    posxs_kernel<<<dim3(SN/256, BN), 256, 0, stream>>>(pos, Wpos, bpos, ls, xs, sqv);

    // v = src @ Wv^T + bv
    gemm_nt<0><<<dim3(BS/64, 1), 256, 0, stream>>>(srcb, Wvb, bv, (const float*)nullptr,
        (const float*)nullptr, (const float*)nullptr, vws, BS, EN, EN);
    // ctx = softmax(os*exp(-0.5*d2)) @ v
    attn_kernel<<<dim3(256), 256, 0, stream>>>(xs, sqv, vws, os, ctx);
    // x = LN1(src + ctx @ Wo^T + bo)     (residual read in fp32)
    gemm_nt<2><<<dim3(BS/64, 1), 256, 0, stream>>>(ctx, Wob, bo, src, g1, be1,
        xws, BS, EN, EN);
    // h = relu(x @ W1^T + b1)
    gemm_nt<1><<<dim3(BS/64, FN/256), 256, 0, stream>>>(xws, W1b, b1, (const float*)nullptr,
        (const float*)nullptr, (const float*)nullptr, hws, BS, FN, EN);
    // out = LN2(x + h @ W2^T + b2)   -> fp32 output
    gemm_nt<2><<<dim3(BS/64, 1), 256, 0, stream>>>(hws, W2b, b2, xws, g2, be2,
        (float*)d_out, BS, EN, FN);
}

// Round 4
// 374.919 us; speedup vs baseline: 1.5401x; 1.5401x over previous
//
#include <hip/hip_runtime.h>
#include <stdint.h>

#define BN 4
#define SN 4096
#define EN 256
#define PN 32
#define FN 1024
#define BS (BN*SN)   // 16384
#define PAUG 48      // 32 xs channels + (-sq/2, 1) aug + pad to 3*K16

typedef uint16_t bf16_t;
typedef short v4s  __attribute__((ext_vector_type(4)));
typedef short v8s  __attribute__((ext_vector_type(8)));
typedef __bf16 bf16x8 __attribute__((ext_vector_type(8)));
typedef float v4f   __attribute__((ext_vector_type(4)));
typedef float v16f  __attribute__((ext_vector_type(16)));

#define MFMA16(a,b,c) __builtin_amdgcn_mfma_f32_16x16x32_bf16(a,b,c,0,0,0)
#define MFMA32(a,b,c) __builtin_amdgcn_mfma_f32_32x32x16_bf16(a,b,c,0,0,0)

__device__ __forceinline__ float b2f(bf16_t x){
    uint32_t u = ((uint32_t)x) << 16; float f; __builtin_memcpy(&f, &u, 4); return f;
}
__device__ __forceinline__ bf16_t f2b(float f){
    uint32_t u; __builtin_memcpy(&u, &f, 4);
    u += 0x7FFFu + ((u >> 16) & 1u);           // RNE
    return (bf16_t)(u >> 16);
}
__device__ __forceinline__ bf16x8 ldb8(const bf16_t* p){
    v8s r = *(const v8s*)p; return __builtin_bit_cast(bf16x8, r);
}
__device__ __forceinline__ float ldsc(const float* p){ return *p; }
__device__ __forceinline__ float ldsc(const bf16_t* p){ return b2f(*p); }
__device__ __forceinline__ void stsc(float* p, float v){ *p = v; }
__device__ __forceinline__ void stsc(bf16_t* p, float v){ *p = f2b(v); }

// async global->LDS, 16 B per lane; LDS dest = wave-uniform base + lane*16
typedef const __attribute__((address_space(1))) uint32_t* glds_gp;
typedef __attribute__((address_space(3))) uint32_t* glds_lp;
__device__ __forceinline__ void glds16(const bf16_t* g, bf16_t* l){
    __builtin_amdgcn_global_load_lds((glds_gp)g, (glds_lp)l, 16, 0, 0);
}

// ---------------------------------------------------------------------------
// fp32 -> bf16 converters
// ---------------------------------------------------------------------------
__global__ __launch_bounds__(256) void cvt_kernel(
    const float* __restrict__ in, bf16_t* __restrict__ out)
{
    int i = (blockIdx.x * 256 + threadIdx.x) * 4;
    float4 f = *(const float4*)(in + i);
    v4s o;
    o.x = (short)f2b(f.x); o.y = (short)f2b(f.y);
    o.z = (short)f2b(f.z); o.w = (short)f2b(f.w);
    *(v4s*)(out + i) = o;
}

// all four weight matrices in one launch (segment boundaries are multiples of 1024)
__global__ __launch_bounds__(256) void cvtw_kernel(
    const float* __restrict__ a, bf16_t* __restrict__ da,
    const float* __restrict__ b, bf16_t* __restrict__ db,
    const float* __restrict__ c, bf16_t* __restrict__ dc,
    const float* __restrict__ d, bf16_t* __restrict__ dd)
{
    int i = (blockIdx.x * 256 + threadIdx.x) * 4;
    const float* src; bf16_t* dst; int off;
    if      (i <  65536){ src=a; dst=da; off=i; }
    else if (i < 131072){ src=b; dst=db; off=i- 65536; }
    else if (i < 393216){ src=c; dst=dc; off=i-131072; }
    else                { src=d; dst=dd; off=i-393216; }
    float4 f = *(const float4*)(src + off);
    v4s o;
    o.x = (short)f2b(f.x); o.y = (short)f2b(f.y);
    o.z = (short)f2b(f.z); o.w = (short)f2b(f.w);
    *(v4s*)(dst + off) = o;
}

// ---------------------------------------------------------------------------
// posxs: pe = Wpos @ pos_embed + bpos; xs = pe/ls (bf16).
// Writes augmented key rows [xs, -sq/2, 1, 0..] and query rows [xs, 1, -sq/2, 0..]
// so QK MFMA over 48 channels yields -0.5*d2 directly.
// ---------------------------------------------------------------------------
__global__ __launch_bounds__(256) void posxs_kernel(
    const float* __restrict__ pos, const float* __restrict__ Wp,
    const float* __restrict__ bp,  const float* __restrict__ lsp,
    bf16_t* __restrict__ xk, bf16_t* __restrict__ xq)
{
    __shared__ float Wsh[PN*PN];
    __shared__ float bsh[PN];
    int tid = threadIdx.x;
    for (int i = tid; i < PN*PN; i += 256) Wsh[i] = Wp[i];
    if (tid < PN) bsh[tid] = bp[tid];
    __syncthreads();

    int s = blockIdx.x * 256 + tid;
    int b = blockIdx.y;
    float inv_ls = 1.0f / lsp[0];

    float col[PN];
    #pragma unroll
    for (int p = 0; p < PN; p++) col[p] = pos[((size_t)b*PN + p)*SN + s];

    uint16_t xb[PN];
    float sq = 0.f;
    #pragma unroll 4
    for (int o = 0; o < PN; o++){
        float pe = bsh[o];
        #pragma unroll
        for (int p = 0; p < PN; p++) pe += col[p] * Wsh[o*PN + p];
        uint16_t h = f2b(pe * inv_ls);
        xb[o] = h;
        float xr = b2f(h);
        sq += xr * xr;
    }
    uint16_t m05 = f2b(-0.5f * sq);
    const uint16_t one = 0x3F80;

    size_t base = ((size_t)b*SN + s) * PAUG;
    v8s pk[6];
    #pragma unroll
    for (int c = 0; c < 4; c++)
        #pragma unroll
        for (int j = 0; j < 8; j++) ((short*)&pk[c])[j] = (short)xb[c*8 + j];
    #pragma unroll
    for (int j = 0; j < 8; j++){ ((short*)&pk[4])[j] = 0; ((short*)&pk[5])[j] = 0; }

    ((short*)&pk[4])[0] = (short)m05; ((short*)&pk[4])[1] = (short)one;
    #pragma unroll
    for (int c = 0; c < 6; c++) *(v8s*)(xk + base + c*8) = pk[c];

    ((short*)&pk[4])[0] = (short)one; ((short*)&pk[4])[1] = (short)m05;
    #pragma unroll
    for (int c = 0; c < 6; c++) *(v8s*)(xq + base + c*8) = pk[c];
}

// ---------------------------------------------------------------------------
// gemm_a: out[m][n] = A[m][k]*W[n][k] (+bias, opt relu). Block 64m x 64n, 4 waves.
// W chunk [64n x 32k] staged via global_load_lds, shared by all waves.
// EPI 0: bias->out ; 1: relu ; 3: bias -> transposed store into vt[b][e][s]
// ---------------------------------------------------------------------------
template<int EPI, typename OutT>
__global__ __launch_bounds__(256) void gemm_a(
    const bf16_t* __restrict__ A, const bf16_t* __restrict__ W,
    const float* __restrict__ bias, OutT* __restrict__ out,
    bf16_t* __restrict__ vt, int M, int N, int K)
{
    __shared__ __align__(16) bf16_t Wt[64*32];
    int tid = threadIdx.x;
    int lane = tid & 63, wv = tid >> 6, col = lane & 15, quad = lane >> 4;
    int m0 = blockIdx.x * 64, n0 = blockIdx.y * 64;

    const bf16_t* Arow = A + (size_t)(m0 + wv*16 + col)*K + quad*8;
    const bf16_t* wsrc = W + (size_t)(n0 + (tid>>2))*K + (tid&3)*8;
    bf16_t* ldst = Wt + wv*512;   // bytes: wv*1024

    v4f acc[4];
    #pragma unroll
    for (int t = 0; t < 4; t++) acc[t] = (v4f){0.f,0.f,0.f,0.f};

    for (int ks = 0; ks < K; ks += 32){
        glds16(wsrc + ks, ldst);
        __syncthreads();
        bf16x8 a = ldb8(Arow + ks);
        #pragma unroll
        for (int t = 0; t < 4; t++){
            bf16x8 bf = ldb8(Wt + (t*16 + col)*32 + quad*8);
            acc[t] = MFMA16(a, bf, acc[t]);
        }
        __syncthreads();
    }

    float bfv[4];
    #pragma unroll
    for (int t = 0; t < 4; t++) bfv[t] = bias[n0 + t*16 + col];

    if constexpr (EPI == 3){
        __shared__ uint16_t Tsh[64*74];
        #pragma unroll
        for (int r = 0; r < 4; r++)
            #pragma unroll
            for (int t = 0; t < 4; t++)
                Tsh[(wv*16 + quad*4 + r)*74 + t*16 + col] = f2b(acc[t][r] + bfv[t]);
        __syncthreads();
        int e = tid >> 2, sc = tid & 3;
        int b = m0 >> 12;
        int sl = (m0 & (SN-1)) + sc*16;
        v8s p0, p1;
        #pragma unroll
        for (int i = 0; i < 8; i++) ((short*)&p0)[i] = (short)Tsh[(sc*16 + i)*74 + e];
        #pragma unroll
        for (int i = 0; i < 8; i++) ((short*)&p1)[i] = (short)Tsh[(sc*16 + 8 + i)*74 + e];
        bf16_t* dst = vt + ((size_t)b*EN + n0 + e)*SN + sl;
        *(v8s*)dst = p0;
        *(v8s*)(dst + 8) = p1;
    } else {
        #pragma unroll
        for (int r = 0; r < 4; r++){
            int row = m0 + wv*16 + quad*4 + r;
            #pragma unroll
            for (int t = 0; t < 4; t++){
                float y = acc[t][r] + bfv[t];
                if constexpr (EPI == 1) y = fmaxf(y, 0.f);
                stsc(out + (size_t)row*N + n0 + t*16 + col, y);
            }
        }
    }
}

// ---------------------------------------------------------------------------
// gemm_ln: out = LayerNorm(A@W^T + bias + res), N = 256 fixed. Block 64m x 256n.
// W chunk [256 x 32] staged via global_load_lds (4 per thread), shared by waves.
// ---------------------------------------------------------------------------
template<typename OutT, typename ResT>
__global__ __launch_bounds__(256) void gemm_ln(
    const bf16_t* __restrict__ A, const bf16_t* __restrict__ W,
    const float* __restrict__ bias, const ResT* __restrict__ res,
    const float* __restrict__ gamma, const float* __restrict__ beta,
    OutT* __restrict__ out, int M, int K)
{
    __shared__ __align__(16) bf16_t Wt[256*32];   // 16 KB
    int tid = threadIdx.x;
    int lane = tid & 63, wv = tid >> 6, col = lane & 15, quad = lane >> 4;
    int row0 = blockIdx.x * 64 + wv*16;

    const bf16_t* Arow = A + (size_t)(row0 + col)*K + quad*8;

    v4f acc[16];
    #pragma unroll
    for (int t = 0; t < 16; t++) acc[t] = (v4f){0.f,0.f,0.f,0.f};

    for (int ks = 0; ks < K; ks += 32){
        #pragma unroll
        for (int c = 0; c < 4; c++)
            glds16(W + (size_t)(c*64 + (tid>>2))*K + ks + (tid&3)*8,
                   Wt + c*2048 + wv*512);
        __syncthreads();
        bf16x8 a = ldb8(Arow + ks);
        #pragma unroll
        for (int t = 0; t < 16; t++){
            bf16x8 bf = ldb8(Wt + (t*16 + col)*32 + quad*8);
            acc[t] = MFMA16(a, bf, acc[t]);
        }
        __syncthreads();
    }

    float bfv[16], gf[16], btf[16];
    #pragma unroll
    for (int t = 0; t < 16; t++){
        bfv[t] = bias [t*16 + col];
        gf[t]  = gamma[t*16 + col];
        btf[t] = beta [t*16 + col];
    }
    #pragma unroll
    for (int r = 0; r < 4; r++){
        int row = row0 + quad*4 + r;
        float s1 = 0.f, s2 = 0.f;
        #pragma unroll
        for (int t = 0; t < 16; t++){
            float y = acc[t][r] + bfv[t] + ldsc(res + (size_t)row*EN + t*16 + col);
            acc[t][r] = y;
            s1 += y; s2 += y*y;
        }
        #pragma unroll
        for (int m = 1; m <= 8; m <<= 1){
            s1 += __shfl_xor(s1, m);
            s2 += __shfl_xor(s2, m);
        }
        float mu  = s1 * (1.f/256.f);
        float var = s2 * (1.f/256.f) - mu*mu;
        float rs  = rsqrtf(var + 1e-5f);
        #pragma unroll
        for (int t = 0; t < 16; t++)
            stsc(out + (size_t)row*EN + t*16 + col, (acc[t][r]-mu)*rs*gf[t] + btf[t]);
    }
}

// ---------------------------------------------------------------------------
// Attention: barrier-free k-loop. Per block: 32 queries, 4 waves k-split (1024 k
// each), 32x32x16 MFMAs. QK over 48 aug channels gives st = -0.5*d2; w=exp(sc-os).
// PV B-frags read directly from pre-transposed Vt[b][e][s]. LDS combine at end.
// ---------------------------------------------------------------------------
__global__ __launch_bounds__(256, 2) void attn_kernel(
    const bf16_t* __restrict__ xk, const bf16_t* __restrict__ xq,
    const bf16_t* __restrict__ vt, const float* __restrict__ osp,
    bf16_t* __restrict__ ctx)
{
    __shared__ __align__(16) float bufA[8192];   // 32 KB
    __shared__ __align__(16) float bufB[8192];   // 32 KB
    __shared__ float densh[4][32];

    int tid  = threadIdx.x;
    int lane = tid & 63;
    int wv   = tid >> 6;
    int l31  = lane & 31;
    int half = lane >> 5;

    // XCD-aware: 2 XCDs per batch -> xk/xq/vt L2-resident per XCD pair
    int bid = blockIdx.x;
    int b   = (bid >> 1) & 3;
    int idx = (bid >> 3) + ((bid & 1) << 6);
    int q0  = idx * 32;

    float os = osp[0];
    const float c1 = 1.4426950408889634f;
    float k2 = c1 * os;

    const bf16_t* xkb = xk + (size_t)b * SN * PAUG;
    const bf16_t* xqb = xq + (size_t)b * SN * PAUG;
    const bf16_t* vtb = vt + (size_t)b * EN * SN;

    bf16x8 qf[3];
    #pragma unroll
    for (int pm = 0; pm < 3; pm++)
        qf[pm] = ldb8(xqb + (size_t)(q0 + l31)*PAUG + pm*16 + half*8);

    v16f acc[8];
    #pragma unroll
    for (int et = 0; et < 8; et++)
        #pragma unroll
        for (int i = 0; i < 16; i++) acc[et][i] = 0.f;
    float den = 0.f;

    int k0beg = wv * 1024;
    for (int k0 = k0beg; k0 < k0beg + 1024; k0 += 32){
        v16f st;
        #pragma unroll
        for (int i = 0; i < 16; i++) st[i] = 0.f;
        #pragma unroll
        for (int pm = 0; pm < 3; pm++){
            bf16x8 kf = ldb8(xkb + (size_t)(k0 + l31)*PAUG + pm*16 + half*8);
            st = MFMA32(kf, qf[pm], st);
        }
        // w = exp(os*exp(st_clamped) - os), rounded to bf16 (den matches MFMA input)
        float wr[16];
        #pragma unroll
        for (int rg = 0; rg < 16; rg++){
            float t = fminf(st[rg], 0.f);
            float e = exp2f(c1 * t);
            wr[rg] = b2f(f2b(exp2f(k2 * (e - 1.f))));
            den += wr[rg];
        }
        // C-layout -> A-operand layout via half-swap shuffles; then PV
        #pragma unroll
        for (int pvh = 0; pvh < 2; pvh++){
            int base = 8*pvh;
            float sw[8];
            #pragma unroll
            for (int r = 0; r < 8; r++) sw[r] = __shfl_xor(wr[base + r], 32);
            v8s aw;
            #pragma unroll
            for (int j = 0; j < 8; j++){
                float fv = ((j < 4) == (half == 0)) ? wr[base + j] : sw[(j + 4) & 7];
                ((short*)&aw)[j] = (short)f2b(fv);
            }
            bf16x8 af = __builtin_bit_cast(bf16x8, aw);
            #pragma unroll
            for (int et = 0; et < 8; et++){
                bf16x8 bf = ldb8(vtb + (size_t)(et*32 + l31)*SN + k0 + pvh*16 + half*8);
                acc[et] = MFMA32(af, bf, acc[et]);
            }
        }
    }

    den += __shfl_xor(den, 32);
    if (lane < 32) densh[wv][lane] = den;
    __syncthreads();

    // cross-wave combine: waves 1,3 stage; 0,2 add; 2 stages; 0 adds.
    if (wv == 1 || wv == 3){
        float* buf = (wv == 1) ? bufA : bufB;
        #pragma unroll
        for (int et = 0; et < 8; et++)
            #pragma unroll
            for (int rg = 0; rg < 4; rg++){
                v4f p = { acc[et][rg*4+0], acc[et][rg*4+1], acc[et][rg*4+2], acc[et][rg*4+3] };
                *(v4f*)&buf[(et*4 + rg)*256 + lane*4] = p;
            }
    }
    __syncthreads();
    if (wv == 0 || wv == 2){
        float* buf = (wv == 0) ? bufA : bufB;
        #pragma unroll
        for (int et = 0; et < 8; et++)
            #pragma unroll
            for (int rg = 0; rg < 4; rg++){
                v4f p = *(const v4f*)&buf[(et*4 + rg)*256 + lane*4];
                #pragma unroll
                for (int j = 0; j < 4; j++) acc[et][rg*4+j] += p[j];
            }
    }
    __syncthreads();
    if (wv == 2){
        #pragma unroll
        for (int et = 0; et < 8; et++)
            #pragma unroll
            for (int rg = 0; rg < 4; rg++){
                v4f p = { acc[et][rg*4+0], acc[et][rg*4+1], acc[et][rg*4+2], acc[et][rg*4+3] };
                *(v4f*)&bufA[(et*4 + rg)*256 + lane*4] = p;
            }
    }
    __syncthreads();
    if (wv == 0){
        #pragma unroll
        for (int et = 0; et < 8; et++)
            #pragma unroll
            for (int rg = 0; rg < 4; rg++){
                v4f p = *(const v4f*)&bufA[(et*4 + rg)*256 + lane*4];
                #pragma unroll
                for (int j = 0; j < 4; j++) acc[et][rg*4+j] += p[j];
            }
        size_t obase = ((size_t)b*SN + q0) * EN;
        #pragma unroll
        for (int rg = 0; rg < 16; rg++){
            int row = (rg & 3) + 8*(rg >> 2) + 4*half;
            float dt = densh[0][row] + densh[1][row] + densh[2][row] + densh[3][row];
            float inv = 1.f / dt;
            #pragma unroll
            for (int et = 0; et < 8; et++)
                ctx[obase + (size_t)row*EN + et*32 + l31] = f2b(acc[et][rg] * inv);
        }
    }
}

// ---------------------------------------------------------------------------
extern "C" void kernel_launch(void* const* d_in, const int* in_sizes, int n_in,
                              void* d_out, int out_size, void* d_ws, size_t ws_size,
                              hipStream_t stream)
{
    (void)in_sizes; (void)n_in; (void)out_size; (void)ws_size;
    const float* src  = (const float*)d_in[0];
    const float* pos  = (const float*)d_in[1];
    const float* Wpos = (const float*)d_in[2];
    const float* bpos = (const float*)d_in[3];
    const float* ls   = (const float*)d_in[4];
    const float* os   = (const float*)d_in[5];
    const float* Wv   = (const float*)d_in[6];
    const float* bv   = (const float*)d_in[7];
    const float* Wo   = (const float*)d_in[8];
    const float* bo   = (const float*)d_in[9];
    const float* W1   = (const float*)d_in[10];
    const float* b1   = (const float*)d_in[11];
    const float* W2   = (const float*)d_in[12];
    const float* b2   = (const float*)d_in[13];
    const float* g1   = (const float*)d_in[14];
    const float* be1  = (const float*)d_in[15];
    const float* g2   = (const float*)d_in[16];
    const float* be2  = (const float*)d_in[17];

    char* w = (char*)d_ws;
    bf16_t* xkb  = (bf16_t*)(w);                         // 1.5 MB [B,S,48]
    bf16_t* xqb  = (bf16_t*)(w + ( 2u<<20));             // 1.5 MB
    bf16_t* Wvb  = (bf16_t*)(w + ( 4u<<20));             // 128 KB
    bf16_t* Wob  = (bf16_t*)(w + ( 4u<<20) + (1u<<18));  // 128 KB
    bf16_t* W1b  = (bf16_t*)(w + ( 5u<<20));             // 512 KB
    bf16_t* W2b  = (bf16_t*)(w + ( 6u<<20));             // 512 KB
    bf16_t* srcb = (bf16_t*)(w + ( 8u<<20));             // 8 MB (dead after wv-gemm)
    bf16_t* ctx  = (bf16_t*)(w + ( 8u<<20));             // aliases srcb
    bf16_t* vtg  = (bf16_t*)(w + (16u<<20));             // 8 MB [B,E,S]
    bf16_t* xws  = (bf16_t*)(w + (24u<<20));             // 8 MB
    bf16_t* hws  = (bf16_t*)(w + (32u<<20));             // 32 MB

    cvt_kernel<<<dim3((BS*EN)>>10), 256, 0, stream>>>(src, srcb);
    cvtw_kernel<<<dim3(640), 256, 0, stream>>>(Wv, Wvb, Wo, Wob, W1, W1b, W2, W2b);
    posxs_kernel<<<dim3(SN/256, BN), 256, 0, stream>>>(pos, Wpos, bpos, ls, xkb, xqb);

    // v = src @ Wv^T + bv  -> stored transposed as vt[b][e][s]
    gemm_a<3, bf16_t><<<dim3(BS/64, EN/64), 256, 0, stream>>>(
        srcb, Wvb, bv, (bf16_t*)nullptr, vtg, BS, EN, EN);
    // ctx = softmax(os*exp(-0.5*d2)) @ v
    attn_kernel<<<dim3(512), 256, 0, stream>>>(xkb, xqb, vtg, os, ctx);
    // x = LN1(src + ctx @ Wo^T + bo)
    gemm_ln<bf16_t, float><<<dim3(BS/64), 256, 0, stream>>>(
        ctx, Wob, bo, src, g1, be1, xws, BS, EN);
    // h = relu(x @ W1^T + b1)
    gemm_a<1, bf16_t><<<dim3(BS/64, FN/64), 256, 0, stream>>>(
        xws, W1b, b1, hws, (bf16_t*)nullptr, BS, FN, EN);
    // out = LN2(x + h @ W2^T + b2) -> fp32
    gemm_ln<float, bf16_t><<<dim3(BS/64), 256, 0, stream>>>(
        hws, W2b, b2, xws, g2, be2, (float*)d_out, BS, FN);
}